// Round 3
// baseline (142.541 us; speedup 1.0000x reference)
//
#include <hip/hip_runtime.h>

// Problem constants (from reference setup_inputs)
constexpr int Bn = 16, Cn = 4, Hn = 512, Wn = 512, Nn = 8192;
constexpr int BLOCK = 256;
constexpr int GRID  = 1024;            // 128 blocks per XCD -> 4 blocks/CU, 16 waves/CU
constexpr int PHASES = 4;              // 2 planes per XCD per phase -> 2 MiB hot << 4 MiB L2

typedef int iv4 __attribute__((ext_vector_type(4)));

// good-interval counts per class c: set0 [1,1,2,1], set1 [0,1,0,2]
__device__ __forceinline__ int good_of(int s, int c) {
    return (s == 0) ? ((c == 2) ? 2 : 1)
                    : ((c == 1) ? 1 : ((c == 3) ? 2 : 0));
}

__global__ __launch_bounds__(BLOCK) void bd_fused(
        const float* __restrict__ pred,
        const iv4* __restrict__ iv0,
        const iv4* __restrict__ iv1,
        float* __restrict__ partials,
        unsigned* __restrict__ counter,
        float* __restrict__ out) {
    // XCD-affinity: blocks with blockIdx%8==x land on XCD x (round-robin dispatch).
    // Each XCD owns the 8 planes p ≡ x (mod 8), swept in 4 phases of 2 planes so
    // only ~2 MiB of pred is hot per XCD L2. Phases separated by RAW s_barrier
    // (no compiler vmcnt(0) drain) and software-pipelined depth-1 (round-2
    // structure, best measured). Final reduction fused via last-block-done:
    // eliminates the 1-block bd_final dispatch + its launch gap (~6 µs).
    const int m   = blockIdx.x;
    const int xcd = m & 7;
    const int r   = m >> 3;                      // [0,128)
    const int idx = r * BLOCK + threadIdx.x;     // [0,32768)
    const int u   = idx >> 14;                   // plane of the phase pair (block-uniform)
    const int s   = (idx >> 13) & 1;             // interval set (block-uniform)
    const int e   = idx & (Nn - 1);              // entry within plane

    const iv4* __restrict__ iv = s ? iv1 : iv0;

    // All interval quads in flight up-front (independent 16B coalesced loads,
    // non-temporal so the 16 MiB stream doesn't evict pred lines from L2).
    iv4 A[PHASES];
    #pragma unroll
    for (int j = 0; j < PHASES; ++j) {
        const int p = (2 * j + u) * 8 + xcd;     // plane = b*C + c
        A[j] = __builtin_nontemporal_load(&iv[p * Nn + e]);
    }

    float bs[PHASES], ds[PHASES];

    // Prologue: phase 0 gathers.
    {
        const float* __restrict__ plane = pred + (size_t)(u * 8 + xcd) * (Hn * Wn);
        bs[0] = plane[(A[0].x << 9) + A[0].y];   // W=512 -> <<9
        ds[0] = plane[(A[0].z << 9) + A[0].w];
    }

    float acc = 0.0f;
    #pragma unroll
    for (int j = 0; j < PHASES; ++j) {
        // Issue next phase's gathers before consuming this phase (stay in flight
        // across the raw barrier; compiler emits partial vmcnt for the consume).
        if (j + 1 < PHASES) {
            const int pn = (2 * (j + 1) + u) * 8 + xcd;
            const float* __restrict__ plane = pred + (size_t)pn * (Hn * Wn);
            bs[j + 1] = plane[(A[j + 1].x << 9) + A[j + 1].y];
            ds[j + 1] = plane[(A[j + 1].z << 9) + A[j + 1].w];
        }
        const int p = (2 * j + u) * 8 + xcd;
        const int c = p & (Cn - 1);
        float d = bs[j] - ds[j]; d *= d;
        acc += (e < good_of(s, c)) ? (1.0f - d) : d;   // same order: bit-identical
        if (j + 1 < PHASES)
            __builtin_amdgcn_s_barrier();        // align phases, NO vmcnt(0) drain
    }

    // wave-64 butterfly reduce (unchanged)
    #pragma unroll
    for (int off = 32; off > 0; off >>= 1)
        acc += __shfl_down(acc, off, 64);

    __shared__ float wsum[BLOCK / 64];
    __shared__ bool  lastFlag;
    const int lane = threadIdx.x & 63;
    const int wave = threadIdx.x >> 6;
    if (lane == 0) wsum[wave] = acc;
    __syncthreads();
    if (threadIdx.x == 0) {
        partials[m] = wsum[0] + wsum[1] + wsum[2] + wsum[3];
        __threadfence();                          // device-scope release (cross-XCD)
        unsigned old = atomicAdd(counter, 1u);    // device-scope by default (m20)
        lastFlag = (old == GRID - 1);
    }
    __syncthreads();                              // publishes lastFlag; also orders
                                                  // earlier wsum read before reuse
    if (!lastFlag) return;

    // Last-arriving block: identical reduction bd_final performed (same order,
    // bit-identical result). No spin-wait: counter==GRID-1 + acquire fence
    // guarantees all partials are visible.
    __threadfence();                              // device-scope acquire
    float facc = 0.0f;
    #pragma unroll
    for (int i = 0; i < GRID / BLOCK; ++i)
        facc += partials[threadIdx.x + i * BLOCK];

    #pragma unroll
    for (int off = 32; off > 0; off >>= 1)
        facc += __shfl_down(facc, off, 64);

    if (lane == 0) wsum[wave] = facc;
    __syncthreads();
    if (threadIdx.x == 0)
        out[0] = wsum[0] + wsum[1] + wsum[2] + wsum[3];
}

extern "C" void kernel_launch(void* const* d_in, const int* in_sizes, int n_in,
                              void* d_out, int out_size, void* d_ws, size_t ws_size,
                              hipStream_t stream) {
    const float* pred = (const float*)d_in[0];
    const iv4*   iv0  = (const iv4*)d_in[1];
    const iv4*   iv1  = (const iv4*)d_in[2];
    float* out      = (float*)d_out;
    float* partials = (float*)d_ws;                               // GRID floats
    unsigned* counter = (unsigned*)((char*)d_ws + GRID * sizeof(float));

    // Workspace is poisoned between runs: zero the 4-byte arrival counter on
    // the stream (graph-capture legal; tiny fill dispatch).
    hipMemsetAsync(counter, 0, sizeof(unsigned), stream);

    bd_fused<<<GRID, BLOCK, 0, stream>>>(pred, iv0, iv1, partials, counter, out);
}

// Round 4
// 114.497 us; speedup vs baseline: 1.2449x; 1.2449x over previous
//
#include <hip/hip_runtime.h>

// Problem constants (from reference setup_inputs)
constexpr int Bn = 16, Cn = 4, Hn = 512, Wn = 512, Nn = 8192;
constexpr int BLOCK = 256;
constexpr int GRID  = 1024;            // 128 blocks per XCD -> 4 blocks/CU, 16 waves/CU
constexpr int PHASES = 4;              // 2 planes per XCD per phase -> 2 MiB hot << 4 MiB L2

typedef int iv4 __attribute__((ext_vector_type(4)));

// good-interval counts per class c: set0 [1,1,2,1], set1 [0,1,0,2]
__device__ __forceinline__ int good_of(int s, int c) {
    return (s == 0) ? ((c == 2) ? 2 : 1)
                    : ((c == 1) ? 1 : ((c == 3) ? 2 : 0));
}

__global__ __launch_bounds__(BLOCK) void bd_fused(
        const float* __restrict__ pred,
        const iv4* __restrict__ iv0,
        const iv4* __restrict__ iv1,
        float* __restrict__ partials,
        unsigned* __restrict__ counter,
        float* __restrict__ out) {
    // Round-2 main loop (best measured: ~17 µs inferred) + last-block-done final
    // reduction. Round 3 showed __threadfence() is implemented with L2
    // writeback/invalidate on gfx950 (cross-XCD coherence) -> 1024 in-grid L2
    // flushes destroyed pred locality (67 µs, 650 GB/s, VALU 0.9%). This version
    // uses SCOPED atomics only (per-access sc0/sc1 write-through / L2-bypass):
    // zero cache-maintenance instructions, same cross-XCD visibility guarantee.
    const int m   = blockIdx.x;
    const int xcd = m & 7;
    const int r   = m >> 3;                      // [0,128)
    const int idx = r * BLOCK + threadIdx.x;     // [0,32768)
    const int u   = idx >> 14;                   // plane of the phase pair (block-uniform)
    const int s   = (idx >> 13) & 1;             // interval set (block-uniform)
    const int e   = idx & (Nn - 1);              // entry within plane

    const iv4* __restrict__ iv = s ? iv1 : iv0;

    // All interval quads in flight up-front (independent 16B coalesced loads,
    // non-temporal so the 16 MiB stream doesn't evict pred lines from L2).
    iv4 A[PHASES];
    #pragma unroll
    for (int j = 0; j < PHASES; ++j) {
        const int p = (2 * j + u) * 8 + xcd;     // plane = b*C + c
        A[j] = __builtin_nontemporal_load(&iv[p * Nn + e]);
    }

    float bs[PHASES], ds[PHASES];

    // Prologue: phase 0 gathers.
    {
        const float* __restrict__ plane = pred + (size_t)(u * 8 + xcd) * (Hn * Wn);
        bs[0] = plane[(A[0].x << 9) + A[0].y];   // W=512 -> <<9
        ds[0] = plane[(A[0].z << 9) + A[0].w];
    }

    float acc = 0.0f;
    #pragma unroll
    for (int j = 0; j < PHASES; ++j) {
        // Issue next phase's gathers before consuming this phase (stay in flight
        // across the raw barrier; compiler emits partial vmcnt for the consume).
        if (j + 1 < PHASES) {
            const int pn = (2 * (j + 1) + u) * 8 + xcd;
            const float* __restrict__ plane = pred + (size_t)pn * (Hn * Wn);
            bs[j + 1] = plane[(A[j + 1].x << 9) + A[j + 1].y];
            ds[j + 1] = plane[(A[j + 1].z << 9) + A[j + 1].w];
        }
        const int p = (2 * j + u) * 8 + xcd;
        const int c = p & (Cn - 1);
        float d = bs[j] - ds[j]; d *= d;
        acc += (e < good_of(s, c)) ? (1.0f - d) : d;   // same order: bit-identical
        if (j + 1 < PHASES)
            __builtin_amdgcn_s_barrier();        // align phases, NO vmcnt(0) drain
    }

    // wave-64 butterfly reduce (unchanged)
    #pragma unroll
    for (int off = 32; off > 0; off >>= 1)
        acc += __shfl_down(acc, off, 64);

    __shared__ float wsum[BLOCK / 64];
    __shared__ bool  lastFlag;
    const int lane = threadIdx.x & 63;
    const int wave = threadIdx.x >> 6;
    if (lane == 0) wsum[wave] = acc;
    __syncthreads();
    if (threadIdx.x == 0) {
        const float pval = wsum[0] + wsum[1] + wsum[2] + wsum[3];
        // Agent-scope store: write-through to the coherence point (L3), no L2 flush.
        __hip_atomic_store(&partials[m], pval, __ATOMIC_RELAXED,
                           __HIP_MEMORY_SCOPE_AGENT);
        // Order: partial must be globally visible before the arrival increment.
        asm volatile("s_waitcnt vmcnt(0)" ::: "memory");
        unsigned old = __hip_atomic_fetch_add(counter, 1u, __ATOMIC_RELAXED,
                                              __HIP_MEMORY_SCOPE_AGENT);
        lastFlag = (old == GRID - 1);
    }
    __syncthreads();
    if (!lastFlag) return;

    // Last-arriving block: identical reduction order to bd_final (bit-identical).
    // Agent-scope loads bypass this XCD's L2 and read the write-through values.
    float facc = 0.0f;
    #pragma unroll
    for (int i = 0; i < GRID / BLOCK; ++i)
        facc += __hip_atomic_load(&partials[threadIdx.x + i * BLOCK],
                                  __ATOMIC_RELAXED, __HIP_MEMORY_SCOPE_AGENT);

    #pragma unroll
    for (int off = 32; off > 0; off >>= 1)
        facc += __shfl_down(facc, off, 64);

    if (lane == 0) wsum[wave] = facc;
    __syncthreads();
    if (threadIdx.x == 0)
        out[0] = wsum[0] + wsum[1] + wsum[2] + wsum[3];
}

extern "C" void kernel_launch(void* const* d_in, const int* in_sizes, int n_in,
                              void* d_out, int out_size, void* d_ws, size_t ws_size,
                              hipStream_t stream) {
    const float* pred = (const float*)d_in[0];
    const iv4*   iv0  = (const iv4*)d_in[1];
    const iv4*   iv1  = (const iv4*)d_in[2];
    float* out      = (float*)d_out;
    float* partials = (float*)d_ws;                               // GRID floats
    unsigned* counter = (unsigned*)((char*)d_ws + GRID * sizeof(float));

    // Workspace is poisoned between replays: zero the 4-byte arrival counter on
    // the stream (graph-capture legal; tiny async fill).
    hipMemsetAsync(counter, 0, sizeof(unsigned), stream);

    bd_fused<<<GRID, BLOCK, 0, stream>>>(pred, iv0, iv1, partials, counter, out);
}

// Round 5
// 110.952 us; speedup vs baseline: 1.2847x; 1.0319x over previous
//
#include <hip/hip_runtime.h>

// Problem constants (from reference setup_inputs)
constexpr int Bn = 16, Cn = 4, Hn = 512, Wn = 512, Nn = 8192;
constexpr int BLOCK = 256;
constexpr int GRID  = 1024;            // 128 blocks per XCD -> 4 blocks/CU, 16 waves/CU
constexpr int PHASES = 4;              // 2 planes per XCD per phase -> 2 MiB hot << 4 MiB L2

typedef int iv4 __attribute__((ext_vector_type(4)));

// good-interval counts per class c: set0 [1,1,2,1], set1 [0,1,0,2]
__device__ __forceinline__ int good_of(int s, int c) {
    return (s == 0) ? ((c == 2) ? 2 : 1)
                    : ((c == 1) ? 1 : ((c == 3) ? 2 : 0));
}

__global__ __launch_bounds__(BLOCK) void bd_gather(
        const float* __restrict__ pred,
        const iv4* __restrict__ iv0,
        const iv4* __restrict__ iv1,
        float* __restrict__ partials) {
    // PROVEN-BEST structure (round 2, 108.5 µs total). Do not fuse the final
    // reduction into this kernel: both fusion variants regressed
    //   - __threadfence() last-block-done: 142.5 µs (fence = L2 wb/inv on gfx950,
    //     1024 in-grid flushes destroyed pred L2 locality)
    //   - scoped-atomic last-block-done + counter memset: 114.5 µs (serial tail
    //     + memset gap >= the bd_final dispatch it replaced)
    //
    // XCD-affinity: blocks with blockIdx%8==x land on XCD x (round-robin
    // dispatch). Each XCD owns the 8 planes p ≡ x (mod 8), swept in 4 phases of
    // 2 planes so only ~2 MiB of pred is hot per XCD L2 (8-planes-at-once
    // measured worse: 112.0 µs). Phases separated by RAW s_barrier (no
    // compiler vmcnt(0) drain, unlike __syncthreads) and software-pipelined
    // depth-1: phase j+1's gathers are in flight while phase j is consumed.
    const int m   = blockIdx.x;
    const int xcd = m & 7;
    const int r   = m >> 3;                      // [0,128)
    const int idx = r * BLOCK + threadIdx.x;     // [0,32768)
    const int u   = idx >> 14;                   // plane of the phase pair (block-uniform)
    const int s   = (idx >> 13) & 1;             // interval set (block-uniform)
    const int e   = idx & (Nn - 1);              // entry within plane

    const iv4* __restrict__ iv = s ? iv1 : iv0;

    // All interval quads in flight up-front (independent 16B coalesced loads,
    // non-temporal so the 16 MiB stream doesn't evict pred lines from L2).
    iv4 A[PHASES];
    #pragma unroll
    for (int j = 0; j < PHASES; ++j) {
        const int p = (2 * j + u) * 8 + xcd;     // plane = b*C + c
        A[j] = __builtin_nontemporal_load(&iv[p * Nn + e]);
    }

    float bs[PHASES], ds[PHASES];

    // Prologue: phase 0 gathers.
    {
        const float* __restrict__ plane = pred + (size_t)(u * 8 + xcd) * (Hn * Wn);
        bs[0] = plane[(A[0].x << 9) + A[0].y];   // W=512 -> <<9
        ds[0] = plane[(A[0].z << 9) + A[0].w];
    }

    float acc = 0.0f;
    #pragma unroll
    for (int j = 0; j < PHASES; ++j) {
        // Issue next phase's gathers before consuming this phase (stay in flight
        // across the raw barrier; compiler emits partial vmcnt for the consume).
        if (j + 1 < PHASES) {
            const int pn = (2 * (j + 1) + u) * 8 + xcd;
            const float* __restrict__ plane = pred + (size_t)pn * (Hn * Wn);
            bs[j + 1] = plane[(A[j + 1].x << 9) + A[j + 1].y];
            ds[j + 1] = plane[(A[j + 1].z << 9) + A[j + 1].w];
        }
        const int p = (2 * j + u) * 8 + xcd;
        const int c = p & (Cn - 1);
        float d = bs[j] - ds[j]; d *= d;
        acc += (e < good_of(s, c)) ? (1.0f - d) : d;   // same order: bit-identical
        if (j + 1 < PHASES)
            __builtin_amdgcn_s_barrier();        // align phases, NO vmcnt(0) drain
    }

    // wave-64 butterfly reduce
    #pragma unroll
    for (int off = 32; off > 0; off >>= 1)
        acc += __shfl_down(acc, off, 64);

    __shared__ float wsum[BLOCK / 64];
    const int lane = threadIdx.x & 63;
    const int wave = threadIdx.x >> 6;
    if (lane == 0) wsum[wave] = acc;
    __syncthreads();
    if (threadIdx.x == 0)
        partials[blockIdx.x] = wsum[0] + wsum[1] + wsum[2] + wsum[3];
}

__global__ __launch_bounds__(BLOCK) void bd_final(
        const float* __restrict__ partials,
        float* __restrict__ out) {
    float acc = 0.0f;
    #pragma unroll
    for (int i = 0; i < GRID / BLOCK; ++i)
        acc += partials[threadIdx.x + i * BLOCK];

    #pragma unroll
    for (int off = 32; off > 0; off >>= 1)
        acc += __shfl_down(acc, off, 64);

    __shared__ float wsum[BLOCK / 64];
    const int lane = threadIdx.x & 63;
    const int wave = threadIdx.x >> 6;
    if (lane == 0) wsum[wave] = acc;
    __syncthreads();
    if (threadIdx.x == 0)
        out[0] = wsum[0] + wsum[1] + wsum[2] + wsum[3];
}

extern "C" void kernel_launch(void* const* d_in, const int* in_sizes, int n_in,
                              void* d_out, int out_size, void* d_ws, size_t ws_size,
                              hipStream_t stream) {
    const float* pred = (const float*)d_in[0];
    const iv4*   iv0  = (const iv4*)d_in[1];
    const iv4*   iv1  = (const iv4*)d_in[2];
    float* out      = (float*)d_out;
    float* partials = (float*)d_ws;              // GRID floats = 4 KiB scratch

    bd_gather<<<GRID, BLOCK, 0, stream>>>(pred, iv0, iv1, partials);
    bd_final<<<1, BLOCK, 0, stream>>>(partials, out);
}